// Round 11
// baseline (260.223 us; speedup 1.0000x reference)
//
#include <hip/hip_runtime.h>
#include <cstdint>

typedef __bf16 bf16x8 __attribute__((ext_vector_type(8)));
typedef float f32x4 __attribute__((ext_vector_type(4)));
typedef uint32_t u32x4 __attribute__((ext_vector_type(4)));
typedef unsigned short u16;

#define B_ 4
#define T_ 2048
#define D_ 1024
#define H_ 16
#define HD_ 64
#define M_ (B_*T_)
// attention scale 1/8 with log2(e) folded in, applied in Q epilogue -> softmax uses exp2
#define QSCALE 0.1803368801111204f

__device__ __forceinline__ u16 f2bf(float f) {
  union { float f; uint32_t u; } x; x.f = f;
  uint32_t u = x.u;
  uint32_t r = (u + 0x7FFFu + ((u >> 16) & 1u)) >> 16;
  return (u16)r;
}

// fast pack: 2 fp32 -> packed bf16x2 via v_perm_b32 (2 adds + 1 perm); p>=0 here.
__device__ __forceinline__ uint32_t pkbf(float a, float b) {
  union { float f; uint32_t u; } x, y; x.f = a; y.f = b;
  uint32_t t0 = x.u + 0x8000u, t1 = y.u + 0x8000u;
  return __builtin_amdgcn_perm(t1, t0, 0x07060302u);  // [t0.b2,t0.b3,t1.b2,t1.b3]
}

__device__ __forceinline__ bf16x8 ld8(const u16* p) {
  return *(const bf16x8*)p;
}

// async global->LDS, 16B per lane; lds ptr must be wave-uniform base (HW adds lane*16)
__device__ __forceinline__ void gl_lds16(const u16* g, u16* l) {
  __builtin_amdgcn_global_load_lds(
      (__attribute__((address_space(1))) void*)(g),
      (__attribute__((address_space(3))) void*)(l), 16, 0, 0);
}

// Fused fp32->bf16 convert of x + 4 weight matrices.
__global__ void cvt_all(const float* __restrict__ x, const float* __restrict__ wq,
                        const float* __restrict__ wk, const float* __restrict__ wv,
                        const float* __restrict__ wo,
                        u16* __restrict__ xb, u16* __restrict__ wqb, u16* __restrict__ wkb,
                        u16* __restrict__ wvb, u16* __restrict__ wob) {
  const long NX = (long)M_ * D_;
  long i = ((long)blockIdx.x * 256 + threadIdx.x) * 4;
  const float* s; u16* d; long j;
  if (i < NX) { s = x; d = xb; j = i; }
  else {
    long r = i - NX; int seg = (int)(r >> 20); j = r & ((1 << 20) - 1);
    s = seg == 0 ? wq : seg == 1 ? wk : seg == 2 ? wv : wo;
    d = seg == 0 ? wqb : seg == 1 ? wkb : seg == 2 ? wvb : wob;
  }
  float4 v = *(const float4*)(s + j);
  ushort4 o;
  o.x = f2bf(v.x); o.y = f2bf(v.y); o.z = f2bf(v.z); o.w = f2bf(v.w);
  *(ushort4*)(d + j) = o;
}

// ---------------------------------------------------------------------------
// V5b GEMM K-loop = V5 (proven 63us) minus the pre-MFMA lgkm(0) order-pin.
//   Round-10 theory: V5's explicit lgkmcnt(0)+sched_barrier BEFORE mfmaAll
//   forces all 16 ds_reads to retire before the first MFMA issues -> LDS
//   (1536cyc) and MFMA (1242cyc) fully serialized (measured 3150cyc/tile).
//   V5b: ds_reads issued in MFMA-consumption order (af[0], bfr[0..3],
//   af[1..3]) as NORMAL loads; no pin before the MFMA block -> compiler
//   inserts fine-grained counted lgkm waits (m97 evidence: lgkm(4/3/1/0)
//   chains), first MFMA starts after ~10 reads, tail reads hide under MFMA.
//   WAR guarantee preserved by a TRAILING lgkmcnt(0)+sched_barrier(0) after
//   the MFMA block, before vmcnt/s_barrier: all reads drained before any
//   wave crosses the barrier and stages into this buffer (identical ledger
//   to V5; reads cannot sink past their consuming MFMAs). Numerics identical.
//   Buffers/barriers/vmcnt/setprio unchanged from the replay-green V5.
// ---------------------------------------------------------------------------

__device__ __forceinline__ void ldA_one(bf16x8 (&af)[4][2], int mi, const u16* buf,
                                        int wr, int lanem, int quad) {
#pragma unroll
  for (int ks = 0; ks < 2; ++ks) {
    int row = wr * 64 + mi * 16 + lanem;
    int off = row * 64 + ((ks * 32 + quad * 8) ^ ((lanem & 7) << 3));  // u16 units
    af[mi][ks] = ld8(buf + off);
  }
}

__device__ __forceinline__ void ldB_all(bf16x8 (&bfr)[4][2], const u16* buf,
                                        int wc, int lanem, int quad) {
#pragma unroll
  for (int nj = 0; nj < 4; ++nj)
#pragma unroll
    for (int ks = 0; ks < 2; ++ks) {
      int row = 256 + wc * 64 + nj * 16 + lanem;
      int off = row * 64 + ((ks * 32 + quad * 8) ^ ((lanem & 7) << 3));
      bfr[nj][ks] = ld8(buf + off);
    }
}

__device__ __forceinline__ void mfmaAll(f32x4 (&acc)[4][4], const bf16x8 (&af)[4][2],
                                        const bf16x8 (&bfr)[4][2]) {
#pragma unroll
  for (int mi = 0; mi < 4; ++mi)
#pragma unroll
    for (int nj = 0; nj < 4; ++nj)
#pragma unroll
      for (int ks = 0; ks < 2; ++ks)
        acc[mi][nj] = __builtin_amdgcn_mfma_f32_16x16x32_bf16(
            af[mi][ks], bfr[nj][ks], acc[mi][nj], 0, 0, 0);
}

#define GEMM_V5B_KLOOP(Asrc, Bsrc)                                             \
  u16* p0 = &sm.S[0][0][0];                                                    \
  u16* p1 = &sm.S[1][0][0];                                                    \
  u16* p2 = &sm.S[2][0][0];                                                    \
  auto stage = [&](u16* bufbase, int u, int k0) {                              \
    const u16* src = (u < 4)                                                   \
        ? Asrc + (size_t)(m0 + u * 64 + wv * 8 + grow) * D_ + k0 + gcol        \
        : Bsrc + (size_t)(n0 + (u - 4) * 64 + wv * 8 + grow) * D_ + k0 + gcol; \
    gl_lds16(src, bufbase + (u * 64 + wv * 8) * 64);                           \
  };                                                                           \
  _Pragma("unroll")                                                            \
  for (int u = 0; u < 6; ++u) stage(p0, u, 0);                                 \
  _Pragma("unroll")                                                            \
  for (int u = 0; u < 6; ++u) stage(p1, u, 64);                                \
  asm volatile("s_waitcnt vmcnt(6)" ::: "memory");                             \
  __builtin_amdgcn_s_barrier();                                                \
  for (int kt = 0; kt < 16; ++kt) {                                            \
    const int k2 = (kt + 2) << 6;                                              \
    /* ds_reads in MFMA-consumption order; normal loads, no pin after */       \
    ldA_one(af, 0, p0, wr, lanem, quad);                                       \
    ldB_all(bfr, p0, wc, lanem, quad);                                         \
    ldA_one(af, 1, p0, wr, lanem, quad);                                       \
    ldA_one(af, 2, p0, wr, lanem, quad);                                       \
    ldA_one(af, 3, p0, wr, lanem, quad);                                       \
    if (kt < 14) {                                                             \
      stage(p2, 0, k2); stage(p2, 1, k2); stage(p2, 2, k2);                    \
      stage(p2, 3, k2); stage(p2, 4, k2); stage(p2, 5, k2);                    \
    }                                                                          \
    __builtin_amdgcn_s_setprio(1);                                             \
    mfmaAll(acc, af, bfr);                                                     \
    __builtin_amdgcn_s_setprio(0);                                             \
    /* trailing drain: all tile-kt reads retired before the barrier (WAR) */   \
    asm volatile("s_waitcnt lgkmcnt(0)" ::: "memory");                         \
    __builtin_amdgcn_sched_barrier(0);                                         \
    if (kt < 14)       asm volatile("s_waitcnt vmcnt(6)" ::: "memory");        \
    else if (kt == 14) asm volatile("s_waitcnt vmcnt(0)" ::: "memory");        \
    __builtin_amdgcn_s_barrier();                                              \
    u16* t = p0; p0 = p1; p1 = p2; p2 = t;                                     \
  }

__global__ __launch_bounds__(512, 2)
void gemm_qkv(const u16* __restrict__ A, const u16* __restrict__ Bw,
              const float* __restrict__ bq, const float* __restrict__ bk,
              const float* __restrict__ bv,
              u16* __restrict__ qb, u16* __restrict__ kb, u16* __restrict__ vtb) {
  __shared__ union {
    u16 S[3][384][64];   // 3 bufs x (A rows 0..255 | B rows 256..383) x 64k = 144 KiB
    u16 C[256 * 136];    // epilogue bounce: Q/K [256][136]; V uses [128][264]
  } sm;

  const int tid = threadIdx.x;
  const int wv = tid >> 6, lane = tid & 63;
  const int lanem = lane & 15, quad = lane >> 4;
  const int wr = wv >> 1, wc = wv & 1;   // wave grid 4 (M) x 2 (N)

  // XCD-chunked bijective swizzle: 96 consecutive tiles (= 4 m-rows) per XCD
  const int l = ((int)blockIdx.x & 7) * 96 + ((int)blockIdx.x >> 3);
  const int n0 = (l % 24) * 128, m0 = (l / 24) * 256;

  // per-lane pre-swizzled global source (T2 involution, row&7 == grow)
  const int grow = lane >> 3;
  const int gcol = (((lane & 7) ^ grow) * 8);

  f32x4 acc[4][4];
#pragma unroll
  for (int a = 0; a < 4; ++a)
#pragma unroll
    for (int b = 0; b < 4; ++b) acc[a][b] = (f32x4){0.f, 0.f, 0.f, 0.f};

  bf16x8 af[4][2];
  bf16x8 bfr[4][2];

  GEMM_V5B_KLOOP(A, Bw);

  // ---- epilogue: bounce through the (now free) LDS union
  const int seg = n0 >> 10, n0l = n0 & 1023;   // BN=128 divides 1024: no crossing
  const int bb = m0 >> 11, tl0 = m0 & (T_ - 1);

  if (seg == 2) {
    // V: transposed bounce [128 ncol][264 (256 t + pad)], single pass
    __syncthreads();
#pragma unroll
    for (int a = 0; a < 4; ++a)
#pragma unroll
      for (int nj = 0; nj < 4; ++nj) {
        int ncol = wc * 64 + nj * 16 + lanem;
        float bvv = bv[n0l + ncol];
        int mb = wr * 64 + a * 16 + quad * 4;
        ushort4 w4;
        w4.x = f2bf(acc[a][nj][0] + bvv);
        w4.y = f2bf(acc[a][nj][1] + bvv);
        w4.z = f2bf(acc[a][nj][2] + bvv);
        w4.w = f2bf(acc[a][nj][3] + bvv);
        *(ushort4*)&sm.C[ncol * 264 + mb] = w4;
      }
    __syncthreads();
#pragma unroll
    for (int it = 0; it < 8; ++it) {
      int chunk = it * 512 + tid;
      int nrow = chunk >> 5, c8 = chunk & 31;
      int gnl = n0l + nrow;
      int hh = gnl >> 6, hd = gnl & 63;
      *(uint4*)&vtb[(((size_t)bb * H_ + hh) * HD_ + hd) * T_ + tl0 + c8 * 8] =
          *(const uint4*)&sm.C[nrow * 264 + c8 * 8];
    }
  } else {
    // Q/K: [256 t][136 (128 hd-cols + pad)] bounce, single pass
    const float* bias = seg == 0 ? bq : bk;
    u16* out = seg == 0 ? qb : kb;
    const float sc = seg == 0 ? QSCALE : 1.0f;
    __syncthreads();
#pragma unroll
    for (int a = 0; a < 4; ++a)
#pragma unroll
      for (int nj = 0; nj < 4; ++nj) {
        int col = wc * 64 + nj * 16 + lanem;
        float bvv = bias[n0l + col];
        int r = wr * 64 + a * 16 + quad * 4;
#pragma unroll
        for (int i = 0; i < 4; ++i)
          sm.C[(r + i) * 136 + col] = f2bf((acc[a][nj][i] + bvv) * sc);
      }
    __syncthreads();
#pragma unroll
    for (int it = 0; it < 8; ++it) {
      int chunk = it * 512 + tid;
      int row = chunk >> 4, c8 = chunk & 15;
      int col0 = c8 * 8;
      int hh = (n0l + col0) >> 6, hd = col0 & 63;
      int t = tl0 + row;
      *(uint4*)&out[(((size_t)bb * H_ + hh) * T_ + t) * HD_ + hd] =
          *(const uint4*)&sm.C[row * 136 + col0];
    }
  }
}

// Output projection: V5b K-loop, 256x128 tile. Grid 256 blocks = 1 uniform
// round (1 block/CU). Direct fp32 register epilogue (no LDS reuse).
__global__ __launch_bounds__(512, 2)
void gemm_wo(const u16* __restrict__ A, const u16* __restrict__ Bw,
             const float* __restrict__ bias, float* __restrict__ Co) {
  __shared__ union {
    u16 S[3][384][64];
    u16 C[256 * 136];
  } sm;

  const int tid = threadIdx.x;
  const int wv = tid >> 6, lane = tid & 63;
  const int lanem = lane & 15, quad = lane >> 4;
  const int wr = wv >> 1, wc = wv & 1;

  // XCD-chunked swizzle: 32 consecutive tiles (= 4 m-rows of 8 n-cols) per XCD
  const int l = ((int)blockIdx.x & 7) * 32 + ((int)blockIdx.x >> 3);
  const int n0 = (l & 7) * 128, m0 = (l >> 3) * 256;

  const int grow = lane >> 3;
  const int gcol = (((lane & 7) ^ grow) * 8);

  f32x4 acc[4][4];
#pragma unroll
  for (int a = 0; a < 4; ++a)
#pragma unroll
    for (int b = 0; b < 4; ++b) acc[a][b] = (f32x4){0.f, 0.f, 0.f, 0.f};

  bf16x8 af[4][2];
  bf16x8 bfr[4][2];

  GEMM_V5B_KLOOP(A, Bw);

  // direct fp32 epilogue: col = n0+wc*64+nj*16+lanem, row = m0+wr*64+a*16+quad*4+i
#pragma unroll
  for (int nj = 0; nj < 4; ++nj) {
    int gn = n0 + wc * 64 + nj * 16 + lanem;
    float bvv = bias[gn];
#pragma unroll
    for (int a = 0; a < 4; ++a)
#pragma unroll
      for (int i = 0; i < 4; ++i) {
        int gm = m0 + wr * 64 + a * 16 + quad * 4 + i;
        Co[(size_t)gm * D_ + gn] = acc[a][nj][i] + bvv;
      }
  }
}

// ---------------------------------------------------------------------------
// Flash attention — round-7 config (best measured: <=62.9us, replay-green).
// r2 core + setprio around both MFMA clusters; 2 LDS buffers (32 KiB,
// 4 blocks/CU); hardened full-drain barrier per tile. TLP (4 resident
// blocks) is this kernel's latency hider — do not trade occupancy.
// ---------------------------------------------------------------------------
__global__ __launch_bounds__(256, 4)
void flash4(const u16* __restrict__ qb, const u16* __restrict__ kb,
            const u16* __restrict__ vtb, u16* __restrict__ ob) {
  __shared__ u16 Ks[2][2][64][32];   // [buf][dhalf][slot][d32]  (slot = permuted key)
  __shared__ u16 Vs[2][2][64][32];   // [buf][shalf][hd][s32]
  int tid = threadIdx.x, wv = tid >> 6, lane = tid & 63;
  int lanem = lane & 15, quad = lane >> 4;
  int h = blockIdx.y, b = blockIdx.z;
  int z = (int)blockIdx.z;
  int qt = ((int)blockIdx.x ^ ((z & 1) * 15) ^ ((z >> 1) * 3)) & 15;
  size_t bh = (size_t)b * H_ + h;
  int qrow0 = qt * 128 + wv * 32;
  const u16* Qg = qb + (bh * T_ + qrow0) * HD_;
  const u16* Kg = kb + bh * T_ * HD_;
  const u16* Vg = vtb + bh * HD_ * T_;

  // staging: chunk tid -> slot=tid>>2, col8=tid&3; K source row is the permuted key
  int slot = tid >> 2, r = slot & 15;
  int key = (slot >> 5) * 32 + (r >> 2) * 8 + ((slot >> 4) & 1) * 4 + (r & 3);
  const u16* gK = Kg + (size_t)key * HD_ + (tid & 3) * 8;
  const u16* gV = Vg + (size_t)slot * T_ + (tid & 3) * 8;

  // Q as B-operand fragments (B[n=q=lanem][k=d=quad*8+j])
  bf16x8 bq[2][2];
#pragma unroll
  for (int mi = 0; mi < 2; ++mi)
#pragma unroll
    for (int ks = 0; ks < 2; ++ks)
      bq[mi][ks] = ld8(&Qg[(size_t)(mi * 16 + lanem) * HD_ + ks * 32 + quad * 8]);

  f32x4 acc_o[2][4];   // O^T[hd-tile ni][q], C layout
  float lsum[2][4];    // 4 independent partial sums per mi (dep-chain break)
#pragma unroll
  for (int mi = 0; mi < 2; ++mi) {
#pragma unroll
    for (int c = 0; c < 4; ++c) lsum[mi][c] = 0.f;
#pragma unroll
    for (int ni = 0; ni < 4; ++ni) acc_o[mi][ni] = (f32x4){0.f, 0.f, 0.f, 0.f};
  }

  int nIter = qt * 2 + 2;
  int myTiles = (qrow0 >> 6) + 1;

#define STAGE_KV(bufi, s0c)                                                 \
  do {                                                                      \
    gl_lds16(gK + (size_t)(s0c) * HD_,      &Ks[bufi][0][0][0] + wv * 512); \
    gl_lds16(gK + (size_t)(s0c) * HD_ + 32, &Ks[bufi][1][0][0] + wv * 512); \
    gl_lds16(gV + (s0c),                    &Vs[bufi][0][0][0] + wv * 512); \
    gl_lds16(gV + (s0c) + 32,               &Vs[bufi][1][0][0] + wv * 512); \
  } while (0)

  STAGE_KV(0, 0);
  for (int it = 0; it < nIter; ++it) {
    // hardened barrier: drain ALL outstanding memory ops (incl. the in-flight
    // global_load_lds prefetch) before the workgroup barrier.
    __builtin_amdgcn_s_waitcnt(0);
    __syncthreads();
    if (it + 1 < nIter) STAGE_KV((it + 1) & 1, (it + 1) * 64);
    if (it >= myTiles) continue;
    int s0 = it * 64, buf = it & 1;

    // S^T = K * Q^T : accs[mi][ni][i] = S[q=lanem][key = sl(ni,quad,i)]
    f32x4 accs[2][4];
#pragma unroll
    for (int mi = 0; mi < 2; ++mi)
#pragma unroll
      for (int ni = 0; ni < 4; ++ni) accs[mi][ni] = (f32x4){0.f, 0.f, 0.f, 0.f};
    __builtin_amdgcn_s_setprio(1);
#pragma unroll
    for (int ks = 0; ks < 2; ++ks)
#pragma unroll
      for (int ni = 0; ni < 4; ++ni) {
        bf16x8 kf = ld8(&Ks[buf][ks][ni * 16 + lanem][quad * 8]);
        accs[0][ni] = __builtin_amdgcn_mfma_f32_16x16x32_bf16(kf, bq[0][ks], accs[0][ni], 0, 0, 0);
        accs[1][ni] = __builtin_amdgcn_mfma_f32_16x16x32_bf16(kf, bq[1][ks], accs[1][ni], 0, 0, 0);
      }
    __builtin_amdgcn_s_setprio(0);

    // softmax (no-max, exp2; scale folded into Q): local key of accs[.][ni][i]
    // is sl = (ni>>1)*32 + quad*8 + (ni&1)*4 + i  (the staged permutation).
    // lsum partials indexed by i: four independent accumulation chains.
    if (s0 + 63 > qrow0) {
#pragma unroll
      for (int mi = 0; mi < 2; ++mi) {
        int qg = qrow0 + mi * 16 + lanem;
#pragma unroll
        for (int ni = 0; ni < 4; ++ni)
#pragma unroll
          for (int i = 0; i < 4; ++i) {
            int sl = (ni >> 1) * 32 + quad * 8 + (ni & 1) * 4 + i;
            float p = (s0 + sl > qg) ? 0.f : __builtin_amdgcn_exp2f(accs[mi][ni][i]);
            accs[mi][ni][i] = p;
            lsum[mi][i] += p;
          }
      }
    } else {
#pragma unroll
      for (int mi = 0; mi < 2; ++mi)
#pragma unroll
        for (int ni = 0; ni < 4; ++ni)
#pragma unroll
          for (int i = 0; i < 4; ++i) {
            float p = __builtin_amdgcn_exp2f(accs[mi][ni][i]);
            accs[mi][ni][i] = p;
            lsum[mi][i] += p;
          }
    }

    // pack: accs tiles (2c, 2c+1) -> PV B-frag for s-chunk c, directly in regs
#pragma unroll
    for (int c = 0; c < 2; ++c) {
      u32x4 pk0, pk1;
      pk0[0] = pkbf(accs[0][c * 2][0], accs[0][c * 2][1]);
      pk0[1] = pkbf(accs[0][c * 2][2], accs[0][c * 2][3]);
      pk0[2] = pkbf(accs[0][c * 2 + 1][0], accs[0][c * 2 + 1][1]);
      pk0[3] = pkbf(accs[0][c * 2 + 1][2], accs[0][c * 2 + 1][3]);
      pk1[0] = pkbf(accs[1][c * 2][0], accs[1][c * 2][1]);
      pk1[1] = pkbf(accs[1][c * 2][2], accs[1][c * 2][3]);
      pk1[2] = pkbf(accs[1][c * 2 + 1][0], accs[1][c * 2 + 1][1]);
      pk1[3] = pkbf(accs[1][c * 2 + 1][2], accs[1][c * 2 + 1][3]);
      bf16x8 bp0 = __builtin_bit_cast(bf16x8, pk0);
      bf16x8 bp1 = __builtin_bit_cast(bf16x8, pk1);
      __builtin_amdgcn_s_setprio(1);
#pragma unroll
      for (int ni = 0; ni < 4; ++ni) {
        bf16x8 vf = ld8(&Vs[buf][c][ni * 16 + lanem][quad * 8]);
        acc_o[0][ni] = __builtin_amdgcn_mfma_f32_16x16x32_bf16(vf, bp0, acc_o[0][ni], 0, 0, 0);
        acc_o[1][ni] = __builtin_amdgcn_mfma_f32_16x16x32_bf16(vf, bp1, acc_o[1][ni], 0, 0, 0);
      }
      __builtin_amdgcn_s_setprio(0);
    }
  }
#undef STAGE_KV

  // epilogue: O^T[hd=ni*16+quad*4+i][q=qrow0+mi*16+lanem] -> ob[q][h*64+hd]
#pragma unroll
  for (int mi = 0; mi < 2; ++mi) {
    float v = (lsum[mi][0] + lsum[mi][1]) + (lsum[mi][2] + lsum[mi][3]);
    v += __shfl_xor(v, 16);
    v += __shfl_xor(v, 32);
    float inv = 1.f / v;
    int q = qrow0 + mi * 16 + lanem;
    u16* og = ob + ((size_t)b * T_ + q) * D_ + h * HD_;
#pragma unroll
    for (int ni = 0; ni < 4; ++ni) {
      ushort4 st;
      st.x = f2bf(acc_o[mi][ni][0] * inv);
      st.y = f2bf(acc_o[mi][ni][1] * inv);
      st.z = f2bf(acc_o[mi][ni][2] * inv);
      st.w = f2bf(acc_o[mi][ni][3] * inv);
      *(ushort4*)(og + ni * 16 + quad * 4) = st;
    }
  }
}

extern "C" void kernel_launch(void* const* d_in, const int* in_sizes, int n_in,
                              void* d_out, int out_size, void* d_ws, size_t ws_size,
                              hipStream_t stream) {
  const float* x  = (const float*)d_in[0];
  const float* wq = (const float*)d_in[1];
  const float* bq = (const float*)d_in[2];
  const float* wk = (const float*)d_in[3];
  const float* bk = (const float*)d_in[4];
  const float* wv = (const float*)d_in[5];
  const float* bv = (const float*)d_in[6];
  const float* wo = (const float*)d_in[7];
  const float* bo = (const float*)d_in[8];

  char* ws = (char*)d_ws;
  const size_t MB = 1ull << 20;
  u16* xb   = (u16*)(ws + 0 * MB);   // [8192,1024] bf16
  u16* wqkv = (u16*)(ws + 16 * MB);  // [3072,1024] bf16 (wq|wk|wv contiguous)
  u16* wob  = (u16*)(ws + 22 * MB);
  u16* qb   = (u16*)(ws + 24 * MB);  // [B,H,T,HD] bf16 (pre-scaled QSCALE)
  u16* kb   = (u16*)(ws + 40 * MB);  // [B,H,T,HD]
  u16* vtb  = (u16*)(ws + 56 * MB);  // [B,H,HD,T]
  u16* ob   = (u16*)(ws + 72 * MB);  // [8192,1024] bf16

  cvt_all<<<(M_ * D_ + 4 * D_ * D_) / 1024, 256, 0, stream>>>(
      x, wq, wk, wv, wo, xb, wqkv, wqkv + (size_t)D_ * D_, wqkv + 2 * (size_t)D_ * D_, wob);

  gemm_qkv<<<768, 512, 0, stream>>>(xb, wqkv, bq, bk, bv, qb, kb, vtb);

  flash4<<<dim3(T_ / 128, H_, B_), 256, 0, stream>>>(qb, kb, vtb, ob);

  gemm_wo<<<256, 512, 0, stream>>>(ob, wob, bo, (float*)d_out);
}

// Round 12
// 247.660 us; speedup vs baseline: 1.0507x; 1.0507x over previous
//
#include <hip/hip_runtime.h>
#include <cstdint>

typedef __bf16 bf16x8 __attribute__((ext_vector_type(8)));
typedef float f32x4 __attribute__((ext_vector_type(4)));
typedef uint32_t u32x4 __attribute__((ext_vector_type(4)));
typedef unsigned short u16;

#define B_ 4
#define T_ 2048
#define D_ 1024
#define H_ 16
#define HD_ 64
#define M_ (B_*T_)
// attention scale 1/8 with log2(e) folded in, applied in Q epilogue -> softmax uses exp2
#define QSCALE 0.1803368801111204f

__device__ __forceinline__ u16 f2bf(float f) {
  union { float f; uint32_t u; } x; x.f = f;
  uint32_t u = x.u;
  uint32_t r = (u + 0x7FFFu + ((u >> 16) & 1u)) >> 16;
  return (u16)r;
}

// fast pack: 2 fp32 -> packed bf16x2 via v_perm_b32 (2 adds + 1 perm); p>=0 here.
__device__ __forceinline__ uint32_t pkbf(float a, float b) {
  union { float f; uint32_t u; } x, y; x.f = a; y.f = b;
  uint32_t t0 = x.u + 0x8000u, t1 = y.u + 0x8000u;
  return __builtin_amdgcn_perm(t1, t0, 0x07060302u);  // [t0.b2,t0.b3,t1.b2,t1.b3]
}

__device__ __forceinline__ bf16x8 ld8(const u16* p) {
  return *(const bf16x8*)p;
}

// async global->LDS, 16B per lane; lds ptr must be wave-uniform base (HW adds lane*16)
__device__ __forceinline__ void gl_lds16(const u16* g, u16* l) {
  __builtin_amdgcn_global_load_lds(
      (__attribute__((address_space(1))) void*)(g),
      (__attribute__((address_space(3))) void*)(l), 16, 0, 0);
}

// Fused fp32->bf16 convert of x + 4 weight matrices.
__global__ void cvt_all(const float* __restrict__ x, const float* __restrict__ wq,
                        const float* __restrict__ wk, const float* __restrict__ wv,
                        const float* __restrict__ wo,
                        u16* __restrict__ xb, u16* __restrict__ wqb, u16* __restrict__ wkb,
                        u16* __restrict__ wvb, u16* __restrict__ wob) {
  const long NX = (long)M_ * D_;
  long i = ((long)blockIdx.x * 256 + threadIdx.x) * 4;
  const float* s; u16* d; long j;
  if (i < NX) { s = x; d = xb; j = i; }
  else {
    long r = i - NX; int seg = (int)(r >> 20); j = r & ((1 << 20) - 1);
    s = seg == 0 ? wq : seg == 1 ? wk : seg == 2 ? wv : wo;
    d = seg == 0 ? wqb : seg == 1 ? wkb : seg == 2 ? wvb : wob;
  }
  float4 v = *(const float4*)(s + j);
  ushort4 o;
  o.x = f2bf(v.x); o.y = f2bf(v.y); o.z = f2bf(v.z); o.w = f2bf(v.w);
  *(ushort4*)(d + j) = o;
}

// ---------------------------------------------------------------------------
// V5 GEMM K-loop (PROVEN best: qkv 62.9-63.5us, replay-green rounds 7/9/10;
// best wall 254.8 in round 10). Round-11 A/B: V5b (no pre-MFMA drain)
// measured IDENTICAL counters (63.0-63.2, MfmaUtil 33.1) -> the drain is not
// the limiter; keep the more-proven V5 form.
//   256x128 tile, BK=64, triple buffer [3][384][64] (144 KiB), ONE barrier
//   per K-tile: [16 ds_read(p0) + 6 stage(p2)]; lgkm(0); setprio(1); 32 MFMA;
//   setprio(0); vmcnt(6); s_barrier; rotate.
// ---------------------------------------------------------------------------

__device__ __forceinline__ void ldA_all(bf16x8 (&af)[4][2], const u16* buf,
                                        int wr, int lanem, int quad) {
#pragma unroll
  for (int mi = 0; mi < 4; ++mi)
#pragma unroll
    for (int ks = 0; ks < 2; ++ks) {
      int row = wr * 64 + mi * 16 + lanem;
      int off = row * 64 + ((ks * 32 + quad * 8) ^ ((lanem & 7) << 3));  // u16 units
      af[mi][ks] = ld8(buf + off);
    }
}

__device__ __forceinline__ void ldB_all(bf16x8 (&bfr)[4][2], const u16* buf,
                                        int wc, int lanem, int quad) {
#pragma unroll
  for (int nj = 0; nj < 4; ++nj)
#pragma unroll
    for (int ks = 0; ks < 2; ++ks) {
      int row = 256 + wc * 64 + nj * 16 + lanem;
      int off = row * 64 + ((ks * 32 + quad * 8) ^ ((lanem & 7) << 3));
      bfr[nj][ks] = ld8(buf + off);
    }
}

__device__ __forceinline__ void mfmaAll(f32x4 (&acc)[4][4], const bf16x8 (&af)[4][2],
                                        const bf16x8 (&bfr)[4][2]) {
#pragma unroll
  for (int mi = 0; mi < 4; ++mi)
#pragma unroll
    for (int nj = 0; nj < 4; ++nj)
#pragma unroll
      for (int ks = 0; ks < 2; ++ks)
        acc[mi][nj] = __builtin_amdgcn_mfma_f32_16x16x32_bf16(
            af[mi][ks], bfr[nj][ks], acc[mi][nj], 0, 0, 0);
}

#define GEMM_V5_KLOOP(Asrc, Bsrc)                                              \
  u16* p0 = &sm.S[0][0][0];                                                    \
  u16* p1 = &sm.S[1][0][0];                                                    \
  u16* p2 = &sm.S[2][0][0];                                                    \
  auto stage = [&](u16* bufbase, int u, int k0) {                              \
    const u16* src = (u < 4)                                                   \
        ? Asrc + (size_t)(m0 + u * 64 + wv * 8 + grow) * D_ + k0 + gcol        \
        : Bsrc + (size_t)(n0 + (u - 4) * 64 + wv * 8 + grow) * D_ + k0 + gcol; \
    gl_lds16(src, bufbase + (u * 64 + wv * 8) * 64);                           \
  };                                                                           \
  _Pragma("unroll")                                                            \
  for (int u = 0; u < 6; ++u) stage(p0, u, 0);                                 \
  _Pragma("unroll")                                                            \
  for (int u = 0; u < 6; ++u) stage(p1, u, 64);                                \
  asm volatile("s_waitcnt vmcnt(6)" ::: "memory");                             \
  __builtin_amdgcn_s_barrier();                                                \
  for (int kt = 0; kt < 16; ++kt) {                                            \
    const int k2 = (kt + 2) << 6;                                              \
    ldA_all(af, p0, wr, lanem, quad);                                          \
    ldB_all(bfr, p0, wc, lanem, quad);                                         \
    if (kt < 14) {                                                             \
      stage(p2, 0, k2); stage(p2, 1, k2); stage(p2, 2, k2);                    \
      stage(p2, 3, k2); stage(p2, 4, k2); stage(p2, 5, k2);                    \
    }                                                                          \
    asm volatile("s_waitcnt lgkmcnt(0)" ::: "memory");                         \
    __builtin_amdgcn_sched_barrier(0);                                         \
    __builtin_amdgcn_s_setprio(1);                                             \
    mfmaAll(acc, af, bfr);                                                     \
    __builtin_amdgcn_s_setprio(0);                                             \
    __builtin_amdgcn_sched_barrier(0);                                         \
    if (kt < 14)       asm volatile("s_waitcnt vmcnt(6)" ::: "memory");        \
    else if (kt == 14) asm volatile("s_waitcnt vmcnt(0)" ::: "memory");        \
    __builtin_amdgcn_s_barrier();                                              \
    u16* t = p0; p0 = p1; p1 = p2; p2 = t;                                     \
  }

__global__ __launch_bounds__(512, 2)
void gemm_qkv(const u16* __restrict__ A, const u16* __restrict__ Bw,
              const float* __restrict__ bq, const float* __restrict__ bk,
              const float* __restrict__ bv,
              u16* __restrict__ qb, u16* __restrict__ kb, u16* __restrict__ vtb) {
  __shared__ union {
    u16 S[3][384][64];   // 3 bufs x (A rows 0..255 | B rows 256..383) x 64k = 144 KiB
    u16 C[256 * 136];    // epilogue bounce: Q/K [256][136]; V uses [128][264]
  } sm;

  const int tid = threadIdx.x;
  const int wv = tid >> 6, lane = tid & 63;
  const int lanem = lane & 15, quad = lane >> 4;
  const int wr = wv >> 1, wc = wv & 1;   // wave grid 4 (M) x 2 (N)

  // XCD-chunked bijective swizzle: 96 consecutive tiles (= 4 m-rows) per XCD
  const int l = ((int)blockIdx.x & 7) * 96 + ((int)blockIdx.x >> 3);
  const int n0 = (l % 24) * 128, m0 = (l / 24) * 256;

  // per-lane pre-swizzled global source (T2 involution, row&7 == grow)
  const int grow = lane >> 3;
  const int gcol = (((lane & 7) ^ grow) * 8);

  f32x4 acc[4][4];
#pragma unroll
  for (int a = 0; a < 4; ++a)
#pragma unroll
    for (int b = 0; b < 4; ++b) acc[a][b] = (f32x4){0.f, 0.f, 0.f, 0.f};

  bf16x8 af[4][2];
  bf16x8 bfr[4][2];

  GEMM_V5_KLOOP(A, Bw);

  // ---- epilogue: bounce through the (now free) LDS union
  const int seg = n0 >> 10, n0l = n0 & 1023;   // BN=128 divides 1024: no crossing
  const int bb = m0 >> 11, tl0 = m0 & (T_ - 1);

  if (seg == 2) {
    // V: transposed bounce [128 ncol][264 (256 t + pad)], single pass
    __syncthreads();
#pragma unroll
    for (int a = 0; a < 4; ++a)
#pragma unroll
      for (int nj = 0; nj < 4; ++nj) {
        int ncol = wc * 64 + nj * 16 + lanem;
        float bvv = bv[n0l + ncol];
        int mb = wr * 64 + a * 16 + quad * 4;
        ushort4 w4;
        w4.x = f2bf(acc[a][nj][0] + bvv);
        w4.y = f2bf(acc[a][nj][1] + bvv);
        w4.z = f2bf(acc[a][nj][2] + bvv);
        w4.w = f2bf(acc[a][nj][3] + bvv);
        *(ushort4*)&sm.C[ncol * 264 + mb] = w4;
      }
    __syncthreads();
#pragma unroll
    for (int it = 0; it < 8; ++it) {
      int chunk = it * 512 + tid;
      int nrow = chunk >> 5, c8 = chunk & 31;
      int gnl = n0l + nrow;
      int hh = gnl >> 6, hd = gnl & 63;
      *(uint4*)&vtb[(((size_t)bb * H_ + hh) * HD_ + hd) * T_ + tl0 + c8 * 8] =
          *(const uint4*)&sm.C[nrow * 264 + c8 * 8];
    }
  } else {
    // Q/K: [256 t][136 (128 hd-cols + pad)] bounce, single pass
    const float* bias = seg == 0 ? bq : bk;
    u16* out = seg == 0 ? qb : kb;
    const float sc = seg == 0 ? QSCALE : 1.0f;
    __syncthreads();
#pragma unroll
    for (int a = 0; a < 4; ++a)
#pragma unroll
      for (int nj = 0; nj < 4; ++nj) {
        int col = wc * 64 + nj * 16 + lanem;
        float bvv = bias[n0l + col];
        int r = wr * 64 + a * 16 + quad * 4;
#pragma unroll
        for (int i = 0; i < 4; ++i)
          sm.C[(r + i) * 136 + col] = f2bf((acc[a][nj][i] + bvv) * sc);
      }
    __syncthreads();
#pragma unroll
    for (int it = 0; it < 8; ++it) {
      int chunk = it * 512 + tid;
      int row = chunk >> 4, c8 = chunk & 15;
      int col0 = c8 * 8;
      int hh = (n0l + col0) >> 6, hd = col0 & 63;
      int t = tl0 + row;
      *(uint4*)&out[(((size_t)bb * H_ + hh) * T_ + t) * HD_ + hd] =
          *(const uint4*)&sm.C[row * 136 + col0];
    }
  }
}

// Output projection: V5 K-loop, 256x128 tile. Grid 256 blocks = 1 uniform
// round (1 block/CU). NEW round-12 epilogue: fp32 LDS bounce for coalesced
// stores — the old direct store wrote 64B segments (16 lanes x 4B per
// quad-row, ~1/4 of ideal store width on 32MB of output). Bounce through
// the free 144KiB union as [256][132] f32 (135KB), then copy out as
// lane-consecutive float4 (512B contiguous per wave). Values bit-identical
// (same adds, just routed through LDS); fully barriered after the K-loop's
// final drain -> no new race surface.
__global__ __launch_bounds__(512, 2)
void gemm_wo(const u16* __restrict__ A, const u16* __restrict__ Bw,
             const float* __restrict__ bias, float* __restrict__ Co) {
  __shared__ union {
    u16 S[3][384][64];
    float Cf[256][132];   // 135,168 B <= 147,456 B
  } sm;

  const int tid = threadIdx.x;
  const int wv = tid >> 6, lane = tid & 63;
  const int lanem = lane & 15, quad = lane >> 4;
  const int wr = wv >> 1, wc = wv & 1;

  // XCD-chunked swizzle: 32 consecutive tiles (= 4 m-rows of 8 n-cols) per XCD
  const int l = ((int)blockIdx.x & 7) * 32 + ((int)blockIdx.x >> 3);
  const int n0 = (l & 7) * 128, m0 = (l >> 3) * 256;

  const int grow = lane >> 3;
  const int gcol = (((lane & 7) ^ grow) * 8);

  f32x4 acc[4][4];
#pragma unroll
  for (int a = 0; a < 4; ++a)
#pragma unroll
    for (int b = 0; b < 4; ++b) acc[a][b] = (f32x4){0.f, 0.f, 0.f, 0.f};

  bf16x8 af[4][2];
  bf16x8 bfr[4][2];

  GEMM_V5_KLOOP(A, Bw);

  // fp32 bounce: all 8 waves write their 64x64 sub-tile (+bias) into Cf
  __syncthreads();
#pragma unroll
  for (int nj = 0; nj < 4; ++nj) {
    int col = wc * 64 + nj * 16 + lanem;
    float bvv = bias[n0 + col];
#pragma unroll
    for (int a = 0; a < 4; ++a) {
      int r = wr * 64 + a * 16 + quad * 4;
#pragma unroll
      for (int i = 0; i < 4; ++i)
        sm.Cf[r + i][col] = acc[a][nj][i] + bvv;
    }
  }
  __syncthreads();
  // coalesced copy-out: 256 rows x 32 float4 chunks = 8192 chunks, 16 iters
#pragma unroll
  for (int it = 0; it < 16; ++it) {
    int chunk = it * 512 + tid;
    int row = chunk >> 5, c4 = chunk & 31;
    *(float4*)&Co[(size_t)(m0 + row) * D_ + n0 + c4 * 4] =
        *(const float4*)&sm.Cf[row][c4 * 4];
  }
}

// ---------------------------------------------------------------------------
// Flash attention — round-7 config (best measured: <=62.9us, replay-green).
// r2 core + setprio around both MFMA clusters; 2 LDS buffers (32 KiB,
// 4 blocks/CU); hardened full-drain barrier per tile. TLP (4 resident
// blocks) is this kernel's latency hider — do not trade occupancy.
// ---------------------------------------------------------------------------
__global__ __launch_bounds__(256, 4)
void flash4(const u16* __restrict__ qb, const u16* __restrict__ kb,
            const u16* __restrict__ vtb, u16* __restrict__ ob) {
  __shared__ u16 Ks[2][2][64][32];   // [buf][dhalf][slot][d32]  (slot = permuted key)
  __shared__ u16 Vs[2][2][64][32];   // [buf][shalf][hd][s32]
  int tid = threadIdx.x, wv = tid >> 6, lane = tid & 63;
  int lanem = lane & 15, quad = lane >> 4;
  int h = blockIdx.y, b = blockIdx.z;
  int z = (int)blockIdx.z;
  int qt = ((int)blockIdx.x ^ ((z & 1) * 15) ^ ((z >> 1) * 3)) & 15;
  size_t bh = (size_t)b * H_ + h;
  int qrow0 = qt * 128 + wv * 32;
  const u16* Qg = qb + (bh * T_ + qrow0) * HD_;
  const u16* Kg = kb + bh * T_ * HD_;
  const u16* Vg = vtb + bh * HD_ * T_;

  // staging: chunk tid -> slot=tid>>2, col8=tid&3; K source row is the permuted key
  int slot = tid >> 2, r = slot & 15;
  int key = (slot >> 5) * 32 + (r >> 2) * 8 + ((slot >> 4) & 1) * 4 + (r & 3);
  const u16* gK = Kg + (size_t)key * HD_ + (tid & 3) * 8;
  const u16* gV = Vg + (size_t)slot * T_ + (tid & 3) * 8;

  // Q as B-operand fragments (B[n=q=lanem][k=d=quad*8+j])
  bf16x8 bq[2][2];
#pragma unroll
  for (int mi = 0; mi < 2; ++mi)
#pragma unroll
    for (int ks = 0; ks < 2; ++ks)
      bq[mi][ks] = ld8(&Qg[(size_t)(mi * 16 + lanem) * HD_ + ks * 32 + quad * 8]);

  f32x4 acc_o[2][4];   // O^T[hd-tile ni][q], C layout
  float lsum[2][4];    // 4 independent partial sums per mi (dep-chain break)
#pragma unroll
  for (int mi = 0; mi < 2; ++mi) {
#pragma unroll
    for (int c = 0; c < 4; ++c) lsum[mi][c] = 0.f;
#pragma unroll
    for (int ni = 0; ni < 4; ++ni) acc_o[mi][ni] = (f32x4){0.f, 0.f, 0.f, 0.f};
  }

  int nIter = qt * 2 + 2;
  int myTiles = (qrow0 >> 6) + 1;

#define STAGE_KV(bufi, s0c)                                                 \
  do {                                                                      \
    gl_lds16(gK + (size_t)(s0c) * HD_,      &Ks[bufi][0][0][0] + wv * 512); \
    gl_lds16(gK + (size_t)(s0c) * HD_ + 32, &Ks[bufi][1][0][0] + wv * 512); \
    gl_lds16(gV + (s0c),                    &Vs[bufi][0][0][0] + wv * 512); \
    gl_lds16(gV + (s0c) + 32,               &Vs[bufi][1][0][0] + wv * 512); \
  } while (0)

  STAGE_KV(0, 0);
  for (int it = 0; it < nIter; ++it) {
    // hardened barrier: drain ALL outstanding memory ops (incl. the in-flight
    // global_load_lds prefetch) before the workgroup barrier.
    __builtin_amdgcn_s_waitcnt(0);
    __syncthreads();
    if (it + 1 < nIter) STAGE_KV((it + 1) & 1, (it + 1) * 64);
    if (it >= myTiles) continue;
    int s0 = it * 64, buf = it & 1;

    // S^T = K * Q^T : accs[mi][ni][i] = S[q=lanem][key = sl(ni,quad,i)]
    f32x4 accs[2][4];
#pragma unroll
    for (int mi = 0; mi < 2; ++mi)
#pragma unroll
      for (int ni = 0; ni < 4; ++ni) accs[mi][ni] = (f32x4){0.f, 0.f, 0.f, 0.f};
    __builtin_amdgcn_s_setprio(1);
#pragma unroll
    for (int ks = 0; ks < 2; ++ks)
#pragma unroll
      for (int ni = 0; ni < 4; ++ni) {
        bf16x8 kf = ld8(&Ks[buf][ks][ni * 16 + lanem][quad * 8]);
        accs[0][ni] = __builtin_amdgcn_mfma_f32_16x16x32_bf16(kf, bq[0][ks], accs[0][ni], 0, 0, 0);
        accs[1][ni] = __builtin_amdgcn_mfma_f32_16x16x32_bf16(kf, bq[1][ks], accs[1][ni], 0, 0, 0);
      }
    __builtin_amdgcn_s_setprio(0);

    // softmax (no-max, exp2; scale folded into Q): local key of accs[.][ni][i]
    // is sl = (ni>>1)*32 + quad*8 + (ni&1)*4 + i  (the staged permutation).
    // lsum partials indexed by i: four independent accumulation chains.
    if (s0 + 63 > qrow0) {
#pragma unroll
      for (int mi = 0; mi < 2; ++mi) {
        int qg = qrow0 + mi * 16 + lanem;
#pragma unroll
        for (int ni = 0; ni < 4; ++ni)
#pragma unroll
          for (int i = 0; i < 4; ++i) {
            int sl = (ni >> 1) * 32 + quad * 8 + (ni & 1) * 4 + i;
            float p = (s0 + sl > qg) ? 0.f : __builtin_amdgcn_exp2f(accs[mi][ni][i]);
            accs[mi][ni][i] = p;
            lsum[mi][i] += p;
          }
      }
    } else {
#pragma unroll
      for (int mi = 0; mi < 2; ++mi)
#pragma unroll
        for (int ni = 0; ni < 4; ++ni)
#pragma unroll
          for (int i = 0; i < 4; ++i) {
            float p = __builtin_amdgcn_exp2f(accs[mi][ni][i]);
            accs[mi][ni][i] = p;
            lsum[mi][i] += p;
          }
    }

    // pack: accs tiles (2c, 2c+1) -> PV B-frag for s-chunk c, directly in regs
#pragma unroll
    for (int c = 0; c < 2; ++c) {
      u32x4 pk0, pk1;
      pk0[0] = pkbf(accs[0][c * 2][0], accs[0][c * 2][1]);
      pk0[1] = pkbf(accs[0][c * 2][2], accs[0][c * 2][3]);
      pk0[2] = pkbf(accs[0][c * 2 + 1][0], accs[0][c * 2 + 1][1]);
      pk0[3] = pkbf(accs[0][c * 2 + 1][2], accs[0][c * 2 + 1][3]);
      pk1[0] = pkbf(accs[1][c * 2][0], accs[1][c * 2][1]);
      pk1[1] = pkbf(accs[1][c * 2][2], accs[1][c * 2][3]);
      pk1[2] = pkbf(accs[1][c * 2 + 1][0], accs[1][c * 2 + 1][1]);
      pk1[3] = pkbf(accs[1][c * 2 + 1][2], accs[1][c * 2 + 1][3]);
      bf16x8 bp0 = __builtin_bit_cast(bf16x8, pk0);
      bf16x8 bp1 = __builtin_bit_cast(bf16x8, pk1);
      __builtin_amdgcn_s_setprio(1);
#pragma unroll
      for (int ni = 0; ni < 4; ++ni) {
        bf16x8 vf = ld8(&Vs[buf][c][ni * 16 + lanem][quad * 8]);
        acc_o[0][ni] = __builtin_amdgcn_mfma_f32_16x16x32_bf16(vf, bp0, acc_o[0][ni], 0, 0, 0);
        acc_o[1][ni] = __builtin_amdgcn_mfma_f32_16x16x32_bf16(vf, bp1, acc_o[1][ni], 0, 0, 0);
      }
      __builtin_amdgcn_s_setprio(0);
    }
  }
#undef STAGE_KV

  // epilogue: O^T[hd=ni*16+quad*4+i][q=qrow0+mi*16+lanem] -> ob[q][h*64+hd]
#pragma unroll
  for (int mi = 0; mi < 2; ++mi) {
    float v = (lsum[mi][0] + lsum[mi][1]) + (lsum[mi][2] + lsum[mi][3]);
    v += __shfl_xor(v, 16);
    v += __shfl_xor(v, 32);
    float inv = 1.f / v;
    int q = qrow0 + mi * 16 + lanem;
    u16* og = ob + ((size_t)b * T_ + q) * D_ + h * HD_;
#pragma unroll
    for (int ni = 0; ni < 4; ++ni) {
      ushort4 st;
      st.x = f2bf(acc_o[mi][ni][0] * inv);
      st.y = f2bf(acc_o[mi][ni][1] * inv);
      st.z = f2bf(acc_o[mi][ni][2] * inv);
      st.w = f2bf(acc_o[mi][ni][3] * inv);
      *(ushort4*)(og + ni * 16 + quad * 4) = st;
    }
  }
}

extern "C" void kernel_launch(void* const* d_in, const int* in_sizes, int n_in,
                              void* d_out, int out_size, void* d_ws, size_t ws_size,
                              hipStream_t stream) {
  const float* x  = (const float*)d_in[0];
  const float* wq = (const float*)d_in[1];
  const float* bq = (const float*)d_in[2];
  const float* wk = (const float*)d_in[3];
  const float* bk = (const float*)d_in[4];
  const float* wv = (const float*)d_in[5];
  const float* bv = (const float*)d_in[6];
  const float* wo = (const float*)d_in[7];
  const float* bo = (const float*)d_in[8];

  char* ws = (char*)d_ws;
  const size_t MB = 1ull << 20;
  u16* xb   = (u16*)(ws + 0 * MB);   // [8192,1024] bf16
  u16* wqkv = (u16*)(ws + 16 * MB);  // [3072,1024] bf16 (wq|wk|wv contiguous)
  u16* wob  = (u16*)(ws + 22 * MB);
  u16* qb   = (u16*)(ws + 24 * MB);  // [B,H,T,HD] bf16 (pre-scaled QSCALE)
  u16* kb   = (u16*)(ws + 40 * MB);  // [B,H,T,HD]
  u16* vtb  = (u16*)(ws + 56 * MB);  // [B,H,HD,T]
  u16* ob   = (u16*)(ws + 72 * MB);  // [8192,1024] bf16

  cvt_all<<<(M_ * D_ + 4 * D_ * D_) / 1024, 256, 0, stream>>>(
      x, wq, wk, wv, wo, xb, wqkv, wqkv + (size_t)D_ * D_, wqkv + 2 * (size_t)D_ * D_, wob);

  gemm_qkv<<<768, 512, 0, stream>>>(xb, wqkv, bq, bk, bv, qb, kb, vtb);

  flash4<<<dim3(T_ / 128, H_, B_), 256, 0, stream>>>(qb, kb, vtb, ob);

  gemm_wo<<<256, 512, 0, stream>>>(ob, wob, bo, (float*)d_out);
}